// Round 7
// baseline (680.873 us; speedup 1.0000x reference)
//
#include <hip/hip_runtime.h>

// Ensemble of 8 LSTMs (H=64, input dim 1) over T=1024, B=128, then (B,T)@Wl^T+bl.
//
// v7 = v6 + SIMD-level latency interleave.
//  - v6 ran 1024 single-wave blocks -> exactly 1 wave/SIMD: MFMA issue gap
//    (~16.7 cyc/MFMA observed = MfmaUtil 46% x 1165 cyc/step / 32 MFMA), LDS
//    ping-pong latency and trans chains fully exposed.
//  - v7 packs 8 INDEPENDENT single-wave chains per 512-thread block ->
//    128 blocks, 1 block/CU, 2 waves/SIMD. No __syncthreads anywhere: each
//    wave owns private LDS slices (x 4KB fp32, ring 2KB bf16, hbuf 256B;
//    50KB/block). Co-resident waves interleave MFMA passes + hide latency.
//  - math identical to v6: A = h broadcast to all 16 rows; lane L owns unit L
//    (2 cndmask select over 4 unit-tiles); Whh bf16 in VGPRs pre-scaled by
//    1/ln2 (tanh gate 2/ln2); h bf16 ping-pong; 32 MFMA + 10 trans per step.

#define LENA 8
#define NB 128
#define NT 1024
#define NH 64
#define WPB 8   // independent waves (chains) per block

typedef __attribute__((ext_vector_type(4))) float f32x4;
typedef __attribute__((ext_vector_type(8))) short bf16x8;

__device__ __forceinline__ short f2bf(float f) {
    unsigned u = __float_as_uint(f);
    unsigned r = (u + 0x7FFFu + ((u >> 16) & 1u)) >> 16;
    return (short)r;
}
__device__ __forceinline__ float bf2f(unsigned short s) {
    return __uint_as_float(((unsigned)s) << 16);
}

__global__ __launch_bounds__(64 * WPB, 1) void lstm_v7_kernel(
    const float* __restrict__ x, const float* __restrict__ hn,
    const float* __restrict__ Wih, const float* __restrict__ Whh,
    const float* __restrict__ bih, const float* __restrict__ bhh,
    const float* __restrict__ Wl, float* __restrict__ ws)
{
    __shared__ float x_all[WPB][NT];                      // 32 KB (per-wave x)
    __shared__ unsigned short ring_all[WPB][NT];          // 16 KB (per-wave h63 history, bf16)
    __shared__ __align__(16) short hb_all[WPB][2][NH];    // 2 KB (per-wave ping-pong h, bf16)

    const int w   = threadIdx.x >> 6;   // wave within block = chain slot
    const int l   = threadIdx.x & 63;   // lane; owns cell/unit l
    const int c   = blockIdx.x * WPB + w;   // global chain 0..1023
    const int li  = c >> 7;             // LSTM index 0..7
    const int b   = c & 127;            // batch 0..127
    const int kg  = l >> 4;
    const int col = l & 15;

    // ---- stage x for this wave's batch (coalesced float4, wave-private) ----
    const float4* xb4 = (const float4*)(x + (size_t)b * NT);
    #pragma unroll
    for (int i = 0; i < 4; ++i) {
        float4 v = xb4[l + 64 * i];
        *(float4*)&x_all[w][(l + 64 * i) * 4] = v;
    }
    // ---- stage h0 (bf16) ----
    hb_all[w][0][l] = f2bf(hn[((size_t)li * NB + b) * NH + l]);

    const float RLN2 = 1.44269504f;
    // ---- persistent B-frags: wf[gate][unit-tile][k-half], bf16, pre-scaled ----
    bf16x8 wf[4][4][2];
    #pragma unroll
    for (int g = 0; g < 4; ++g) {
        const float sc = (g == 2) ? 2.0f * RLN2 : RLN2;
        #pragma unroll
        for (int tt = 0; tt < 4; ++tt) {
            const float* rp = Whh + ((size_t)li * 256 + 64 * g + 16 * tt + col) * 64 + kg * 8;
            #pragma unroll
            for (int kh = 0; kh < 2; ++kh) {
                const float* q = rp + kh * 32;
                bf16x8 f;
                #pragma unroll
                for (int e = 0; e < 8; ++e) f[e] = f2bf(sc * q[e]);
                wf[g][tt][kh] = f;
            }
        }
    }
    // ---- per-cell constants (cell = unit l) ----
    float wih4[4], bias4[4];
    #pragma unroll
    for (int g = 0; g < 4; ++g) {
        const float sc = (g == 2) ? 2.0f * RLN2 : RLN2;
        int rowc = li * 256 + 64 * g + l;
        wih4[g]  = sc * Wih[rowc];
        bias4[g] = sc * (bih[rowc] + bhh[rowc]);
    }

    float cst = 0.0f;
    const bool is63 = (l == 63);
    const bool selb0 = (kg & 1) != 0;
    const bool selb1 = (kg & 2) != 0;

    // no barriers: all buffers are wave-private; in-wave LDS ordering via waitcnt
    for (int t = 0; t < NT; ++t) {
        const int p = t & 1;
        const float xv = x_all[w][t];
        bf16x8 a0 = *(const bf16x8*)&hb_all[w][p][kg * 8];        // h[k 0:32) slice
        bf16x8 a1 = *(const bf16x8*)&hb_all[w][p][32 + kg * 8];   // h[k 32:64) slice

        float gs[4];
        #pragma unroll
        for (int g = 0; g < 4; ++g) {
            const f32x4 z = {0.0f, 0.0f, 0.0f, 0.0f};
            f32x4 c0 = __builtin_amdgcn_mfma_f32_16x16x32_bf16(a0, wf[g][0][0], z, 0, 0, 0);
            c0 = __builtin_amdgcn_mfma_f32_16x16x32_bf16(a1, wf[g][0][1], c0, 0, 0, 0);
            f32x4 c1 = __builtin_amdgcn_mfma_f32_16x16x32_bf16(a0, wf[g][1][0], z, 0, 0, 0);
            c1 = __builtin_amdgcn_mfma_f32_16x16x32_bf16(a1, wf[g][1][1], c1, 0, 0, 0);
            f32x4 c2 = __builtin_amdgcn_mfma_f32_16x16x32_bf16(a0, wf[g][2][0], z, 0, 0, 0);
            c2 = __builtin_amdgcn_mfma_f32_16x16x32_bf16(a1, wf[g][2][1], c2, 0, 0, 0);
            f32x4 c3 = __builtin_amdgcn_mfma_f32_16x16x32_bf16(a0, wf[g][3][0], z, 0, 0, 0);
            c3 = __builtin_amdgcn_mfma_f32_16x16x32_bf16(a1, wf[g][3][1], c3, 0, 0, 0);
            float va = selb0 ? c1[0] : c0[0];
            float vb = selb0 ? c3[0] : c2[0];
            gs[g] = selb1 ? vb : va;
        }

        float gi = fmaf(xv, wih4[0], gs[0] + bias4[0]);
        float gf = fmaf(xv, wih4[1], gs[1] + bias4[1]);
        float gg = fmaf(xv, wih4[2], gs[2] + bias4[2]);
        float go = fmaf(xv, wih4[3], gs[3] + bias4[3]);

        float iv = __builtin_amdgcn_rcpf(1.0f + __builtin_amdgcn_exp2f(-gi));
        float fv = __builtin_amdgcn_rcpf(1.0f + __builtin_amdgcn_exp2f(-gf));
        float gt = fmaf(-2.0f, __builtin_amdgcn_rcpf(1.0f + __builtin_amdgcn_exp2f(gg)), 1.0f);
        float ov = __builtin_amdgcn_rcpf(1.0f + __builtin_amdgcn_exp2f(-go));
        cst = fmaf(fv, cst, iv * gt);
        float ct = fmaf(-2.0f, __builtin_amdgcn_rcpf(1.0f + __builtin_amdgcn_exp2f(2.88539008f * cst)), 1.0f);
        float hh = ov * ct;

        short hb = f2bf(hh);
        hb_all[w][p ^ 1][l] = hb;
        if (is63) ring_all[w][t] = (unsigned short)hb;
    }

    // ---- projection (per wave): out[a] = sum_t ring[t] * Wl[a][t] ----
    {
        const int a = l & 7, ch = l >> 3;     // 8 outputs x 8 t-chunks of 128
        const float* wlp = Wl + (size_t)a * NT + ch * 128;
        const unsigned short* rg = &ring_all[w][ch * 128];
        float pacc = 0.0f;
        #pragma unroll 4
        for (int i = 0; i < 32; ++i) {
            uint2 rv = *(const uint2*)&rg[i * 4];
            float4 wv = *(const float4*)&wlp[i * 4];
            pacc = fmaf(bf2f((unsigned short)(rv.x & 0xffffu)), wv.x, pacc);
            pacc = fmaf(bf2f((unsigned short)(rv.x >> 16)),     wv.y, pacc);
            pacc = fmaf(bf2f((unsigned short)(rv.y & 0xffffu)), wv.z, pacc);
            pacc = fmaf(bf2f((unsigned short)(rv.y >> 16)),     wv.w, pacc);
        }
        pacc += __shfl_xor(pacc, 8);
        pacc += __shfl_xor(pacc, 16);
        pacc += __shfl_xor(pacc, 32);
        if (l < 8) ws[(size_t)c * 8 + l] = pacc;
    }
}

__global__ __launch_bounds__(256) void reduce_kernel(
    const float* __restrict__ ws, const float* __restrict__ bl, float* __restrict__ out)
{
    int tid = blockIdx.x * 256 + threadIdx.x;    // 0..1023
    if (tid >= NB * LENA) return;
    int b = tid >> 3, a = tid & 7;
    float s = bl[a];
    #pragma unroll
    for (int li = 0; li < LENA; ++li)
        s += ws[((size_t)li * NB + b) * 8 + a];
    out[tid] = s;
}

extern "C" void kernel_launch(void* const* d_in, const int* in_sizes, int n_in,
                              void* d_out, int out_size, void* d_ws, size_t ws_size,
                              hipStream_t stream) {
    const float* x   = (const float*)d_in[0];
    const float* hn  = (const float*)d_in[1];
    const float* Wih = (const float*)d_in[2];
    const float* Whh = (const float*)d_in[3];
    const float* bih = (const float*)d_in[4];
    const float* bhh = (const float*)d_in[5];
    const float* Wl  = (const float*)d_in[6];
    const float* bl  = (const float*)d_in[7];
    float* out = (float*)d_out;
    float* ws  = (float*)d_ws;   // 1024*8*4 = 32 KB

    lstm_v7_kernel<<<dim3(1024 / WPB), dim3(64 * WPB), 0, stream>>>(
        x, hn, Wih, Whh, bih, bhh, Wl, ws);
    reduce_kernel<<<dim3(4), dim3(256), 0, stream>>>(ws, bl, out);
}

// Round 8
// 279.295 us; speedup vs baseline: 2.4378x; 2.4378x over previous
//
#include <hip/hip_runtime.h>

// Ensemble of 8 LSTMs (H=64, input dim 1) over T=1024, B=128, then (B,T)@Wl^T+bl.
//
// v8: 4-batch chains, batch-replicated A-rows, zero gate-exchange.
//  - 256 blocks (8 L x 32 groups of 4 batches) x 256 threads (4 waves), all CUs.
//  - A(16x64) rows m = h[batch m&3] (4 batches replicated 4x, bf16).
//    B = Whh rows [64g+16w .. +16] (wave w owns unit-tile w), bf16, pre-scaled
//    by 1/ln2 (tanh gate 2/ln2). 8 MFMAs/wave/step (4 gates x 2 K-halves).
//  - D: col=lane&15=unit-in-tile, row=4*(lane>>4)+reg, batch=row&3=reg.
//    Lane (col,kg) selects reg kg -> holds ALL 4 gates of cell
//    (batch kg, unit 16w+col): 1 cell/lane, no cross-lane gate traffic.
//  - h ping-pong in a 32-slot swizzled LDS buffer: slot(b, s=u>>3) = b*8+(s^(2b))
//    -> writes hit all 32 banks (free), b128 reads <=2-way.
//  - 1 __syncthreads per step. h63 ring (fp32) -> projection after loop.
//  - Only 32 VGPRs of weight frags -> no spill (v7's failure mode).

#define LENA 8
#define NB 128
#define NT 1024
#define NH 64

typedef __attribute__((ext_vector_type(4))) float f32x4;
typedef __attribute__((ext_vector_type(8))) short bf16x8;

__device__ __forceinline__ short f2bf(float f) {
    unsigned u = __float_as_uint(f);
    unsigned r = (u + 0x7FFFu + ((u >> 16) & 1u)) >> 16;
    return (short)r;
}

__global__ __launch_bounds__(256, 1) void lstm_v8_kernel(
    const float* __restrict__ x, const float* __restrict__ hn,
    const float* __restrict__ Wih, const float* __restrict__ Whh,
    const float* __restrict__ bih, const float* __restrict__ bhh,
    const float* __restrict__ Wl, float* __restrict__ ws)
{
    __shared__ float x4[NT][4];                      // 16 KB: x for 4 batches
    __shared__ float ring[NT][4];                    // 16 KB: h63 history (fp32)
    __shared__ __align__(16) short hbuf[2][32][8];   // 1 KB: ping-pong h, swizzled slots

    const int tid = threadIdx.x;
    const int w   = tid >> 6;        // wave 0..3: owns unit-tile w (units 16w..16w+15)
    const int l   = tid & 63;
    const int col = l & 15;          // unit-in-tile (D col)
    const int kg  = l >> 4;          // k-group; also this lane's batch
    const int li  = blockIdx.x >> 5; // LSTM 0..7
    const int bg  = blockIdx.x & 31; // batch group
    const int b0  = bg * 4;

    // ---- stage x: x4[t][bb] = x[b0+bb][t] ----
    for (int i = tid; i < 4 * NT; i += 256) {
        int bb = i >> 10, t = i & (NT - 1);
        x4[t][bb] = x[(size_t)(b0 + bb) * NT + t];
    }
    // ---- stage h0 into swizzled hbuf[0] ----
    {
        int b = tid >> 6, u = tid & 63;
        float v = hn[((size_t)li * NB + b0 + b) * NH + u];
        int slot = b * 8 + ((u >> 3) ^ (2 * b));
        hbuf[0][slot][u & 7] = f2bf(v);
    }

    const float RLN2 = 1.44269504f;
    // ---- B-frags: bf[gate][khalf], row = 64g + 16w + col, k = kh*32 + kg*8 + e ----
    bf16x8 bf[4][2];
    #pragma unroll
    for (int g = 0; g < 4; ++g) {
        const float sc = (g == 2) ? 2.0f * RLN2 : RLN2;
        const float* rp = Whh + ((size_t)li * 256 + 64 * g + 16 * w + col) * 64 + kg * 8;
        #pragma unroll
        for (int kh = 0; kh < 2; ++kh) {
            const float* q = rp + kh * 32;
            bf16x8 f;
            #pragma unroll
            for (int e = 0; e < 8; ++e) f[e] = f2bf(sc * q[e]);
            bf[g][kh] = f;
        }
    }
    // ---- per-lane cell constants: cell (b=kg, u=16w+col) ----
    const int u_c = 16 * w + col;
    float wih4[4];
    f32x4 cinit[4];     // bias splat as MFMA C-init (hoisted, zero per-step cost)
    #pragma unroll
    for (int g = 0; g < 4; ++g) {
        const float sc = (g == 2) ? 2.0f * RLN2 : RLN2;
        int rowc = li * 256 + 64 * g + u_c;
        wih4[g] = sc * Wih[rowc];
        float bv = sc * (bih[rowc] + bhh[rowc]);
        cinit[g][0] = bv; cinit[g][1] = bv; cinit[g][2] = bv; cinit[g][3] = bv;
    }

    // ---- A-read slots: A row m holds h[m&3]; lane reads batch b_r = col&3 ----
    const int b_r = col & 3;
    const int s0 = b_r * 8 + (kg ^ (2 * b_r));          // khalf0: units 8kg..+8
    const int s1 = b_r * 8 + ((4 + kg) ^ (2 * b_r));    // khalf1: units 32+8kg..+8
    // ---- h-write slot for this lane's cell ----
    const int wslot = kg * 8 + (((u_c >> 3)) ^ (2 * kg));
    const int wpos  = u_c & 7;
    const bool isring = (u_c == 63);    // wave 3, col 15: 4 lanes (one per batch kg)

    const bool s_lo = (kg & 1) != 0;
    const bool s_hi = (kg & 2) != 0;
    float cst = 0.0f;

    __syncthreads();

    #pragma unroll 2
    for (int t = 0; t < NT; ++t) {
        const int p = t & 1;
        bf16x8 a0 = *(const bf16x8*)&hbuf[p][s0][0];
        bf16x8 a1 = *(const bf16x8*)&hbuf[p][s1][0];
        const float xsel = x4[t][kg];

        f32x4 acc[4];
        #pragma unroll
        for (int g = 0; g < 4; ++g) {
            f32x4 a = __builtin_amdgcn_mfma_f32_16x16x32_bf16(a0, bf[g][0], cinit[g], 0, 0, 0);
            acc[g] = __builtin_amdgcn_mfma_f32_16x16x32_bf16(a1, bf[g][1], a, 0, 0, 0);
        }

        // select reg kg (batch kg) per gate
        float gs[4];
        #pragma unroll
        for (int g = 0; g < 4; ++g) {
            float va = s_lo ? acc[g][1] : acc[g][0];
            float vb = s_lo ? acc[g][3] : acc[g][2];
            gs[g] = s_hi ? vb : va;
        }

        float gi = fmaf(xsel, wih4[0], gs[0]);
        float gf = fmaf(xsel, wih4[1], gs[1]);
        float gg = fmaf(xsel, wih4[2], gs[2]);
        float go = fmaf(xsel, wih4[3], gs[3]);

        float iv = __builtin_amdgcn_rcpf(1.0f + __builtin_amdgcn_exp2f(-gi));
        float fv = __builtin_amdgcn_rcpf(1.0f + __builtin_amdgcn_exp2f(-gf));
        float gt = fmaf(-2.0f, __builtin_amdgcn_rcpf(1.0f + __builtin_amdgcn_exp2f(gg)), 1.0f);
        float ov = __builtin_amdgcn_rcpf(1.0f + __builtin_amdgcn_exp2f(-go));
        cst = fmaf(fv, cst, iv * gt);
        float ct = fmaf(-2.0f, __builtin_amdgcn_rcpf(1.0f + __builtin_amdgcn_exp2f(2.88539008f * cst)), 1.0f);
        float hh = ov * ct;

        hbuf[p ^ 1][wslot][wpos] = f2bf(hh);
        if (isring) ring[t][kg] = hh;
        __syncthreads();
    }

    // ---- projection: thread (b=w, a=l&7, ch=l>>3): sum_t ring[t][b]*Wl[a][t] ----
    {
        const int b = w;
        const int a = l & 7, ch = l >> 3;
        const float* wlp = Wl + (size_t)a * NT + ch * 128;
        const float* rg  = &ring[ch * 128][0];
        float pacc = 0.0f;
        #pragma unroll 4
        for (int i = 0; i < 128; ++i)
            pacc = fmaf(rg[i * 4 + b], wlp[i], pacc);
        pacc += __shfl_xor(pacc, 8);
        pacc += __shfl_xor(pacc, 16);
        pacc += __shfl_xor(pacc, 32);
        if (l < 8) ws[(size_t)blockIdx.x * 32 + b * 8 + a] = pacc;
    }
}

__global__ __launch_bounds__(256) void reduce_kernel(
    const float* __restrict__ ws, const float* __restrict__ bl, float* __restrict__ out)
{
    int tid = blockIdx.x * 256 + threadIdx.x;    // 0..1023
    if (tid >= NB * LENA) return;
    int b = tid >> 3, a = tid & 7;
    int bg = b >> 2, bb = b & 3;
    float s = bl[a];
    #pragma unroll
    for (int li = 0; li < LENA; ++li)
        s += ws[((size_t)(li * 32 + bg)) * 32 + bb * 8 + a];
    out[tid] = s;
}

extern "C" void kernel_launch(void* const* d_in, const int* in_sizes, int n_in,
                              void* d_out, int out_size, void* d_ws, size_t ws_size,
                              hipStream_t stream) {
    const float* x   = (const float*)d_in[0];
    const float* hn  = (const float*)d_in[1];
    const float* Wih = (const float*)d_in[2];
    const float* Whh = (const float*)d_in[3];
    const float* bih = (const float*)d_in[4];
    const float* bhh = (const float*)d_in[5];
    const float* Wl  = (const float*)d_in[6];
    const float* bl  = (const float*)d_in[7];
    float* out = (float*)d_out;
    float* ws  = (float*)d_ws;   // 256*32*4 = 32 KB

    lstm_v8_kernel<<<dim3(256), dim3(256), 0, stream>>>(x, hn, Wih, Whh, bih, bhh, Wl, ws);
    reduce_kernel<<<dim3(4), dim3(256), 0, stream>>>(ws, bl, out);
}